// Round 1
// baseline (130.520 us; speedup 1.0000x reference)
//
#include <hip/hip_runtime.h>
#include <math.h>

// ---- reference hyperparameters ----
#define LIF_STEPS 100
#define ALPHA 0.05f        // dt / tau_rc = 0.001 / 0.02
#define V_THRESH 1.0f
#define RATE_SCALE 10.0f   // 1 / (n_steps * dt)
#define WTA_ITERS 20
#define W_INH (-0.9f)
#define W_EXC (1.1f)

// Simulate the LIF neuron exactly as the reference scan does.
__device__ __forceinline__ float lif_rate(float J) {
    float v = 0.0f;
    float cnt = 0.0f;
    #pragma unroll 4
    for (int s = 0; s < LIF_STEPS; ++s) {
        v = v + ALPHA * (J - v);          // leaky integration
        if (v >= V_THRESH) {              // spike + reset to 0
            cnt += 1.0f;
            v = 0.0f;
        }
    }
    return cnt * RATE_SCALE;
}

// Stage 1: per-token current J = <Q_t, K_t>, then LIF rates. 1 thread / (b,h,t).
__global__ void qk_rates_kernel(const float* __restrict__ Q,
                                const float* __restrict__ K,
                                float* __restrict__ rates, int D) {
    int idx = blockIdx.x * blockDim.x + threadIdx.x;   // b*h*t index
    const float* q = Q + (size_t)idx * D;
    const float* k = K + (size_t)idx * D;
    float J = 0.0f;
    for (int d = 0; d < D; ++d) J += q[d] * k[d];
    rates[idx] = lif_rate(J);
}

// Stage 3: J = rates_inh[token] * V, LIF rates. 1 thread / element.
__global__ void v_rates_kernel(const float* __restrict__ gains,  // (B*H*T)
                               const float* __restrict__ V,
                               float* __restrict__ out, int D) {
    int idx = blockIdx.x * blockDim.x + threadIdx.x;
    float J = gains[idx / 64] * V[idx];   // D == 64 (pow2 -> shift)
    out[idx] = lif_rate(J);
}

// Iterative soft WTA over one row of length BLOCK*ITEMS, fully in registers.
// r <- softmax(r + (exc-inh)*r + inh*sum(r)), repeated WTA_ITERS times.
template<int BLOCK, int ITEMS>
__global__ __launch_bounds__(BLOCK)
void wta_kernel(float* __restrict__ data, int rowStride) {
    constexpr int NW = BLOCK / 64;        // waves per block
    __shared__ float sh[NW];
    const int tid = threadIdx.x;
    float* row = data + (size_t)blockIdx.x * rowStride;

    float r[ITEMS];
    #pragma unroll
    for (int i = 0; i < ITEMS; ++i) r[i] = row[tid + i * BLOCK];

    for (int it = 0; it < WTA_ITERS; ++it) {
        // ---- total = sum(r) across the row (deterministic order) ----
        float loc = 0.0f;
        #pragma unroll
        for (int i = 0; i < ITEMS; ++i) loc += r[i];
        #pragma unroll
        for (int off = 32; off >= 1; off >>= 1) loc += __shfl_down(loc, off);
        __syncthreads();
        if ((tid & 63) == 0) sh[tid >> 6] = loc;
        __syncthreads();
        float total = 0.0f;
        #pragma unroll
        for (int w = 0; w < NW; ++w) total += sh[w];

        // ---- r + (exc - inh)*r + inh*total ----
        #pragma unroll
        for (int i = 0; i < ITEMS; ++i)
            r[i] = r[i] + (W_EXC - W_INH) * r[i] + W_INH * total;

        // ---- softmax: max ----
        float m = -INFINITY;
        #pragma unroll
        for (int i = 0; i < ITEMS; ++i) m = fmaxf(m, r[i]);
        #pragma unroll
        for (int off = 32; off >= 1; off >>= 1) m = fmaxf(m, __shfl_down(m, off));
        __syncthreads();
        if ((tid & 63) == 0) sh[tid >> 6] = m;
        __syncthreads();
        float gmax = -INFINITY;
        #pragma unroll
        for (int w = 0; w < NW; ++w) gmax = fmaxf(gmax, sh[w]);

        // ---- softmax: exp + sum ----
        float s = 0.0f;
        #pragma unroll
        for (int i = 0; i < ITEMS; ++i) { r[i] = expf(r[i] - gmax); s += r[i]; }
        #pragma unroll
        for (int off = 32; off >= 1; off >>= 1) s += __shfl_down(s, off);
        __syncthreads();
        if ((tid & 63) == 0) sh[tid >> 6] = s;
        __syncthreads();
        float gsum = 0.0f;
        #pragma unroll
        for (int w = 0; w < NW; ++w) gsum += sh[w];

        #pragma unroll
        for (int i = 0; i < ITEMS; ++i) r[i] = r[i] / gsum;
    }

    #pragma unroll
    for (int i = 0; i < ITEMS; ++i) row[tid + i * BLOCK] = r[i];
}

extern "C" void kernel_launch(void* const* d_in, const int* in_sizes, int n_in,
                              void* d_out, int out_size, void* d_ws, size_t ws_size,
                              hipStream_t stream) {
    const float* Q = (const float*)d_in[0];
    const float* K = (const float*)d_in[1];
    const float* V = (const float*)d_in[2];
    float* out = (float*)d_out;
    float* rates = (float*)d_ws;          // B*H*T = 4096 floats of scratch

    const int B = 2, H = 8, T = 256, D = 64;
    const int BHT = B * H * T;            // 4096
    const int TOTAL = BHT * D;            // 262144

    // Stage 1: QK dot -> LIF rates (B,H,T)
    qk_rates_kernel<<<BHT / 256, 256, 0, stream>>>(Q, K, rates, D);
    // Stage 2: WTA over the T=256 tokens of each of the 16 heads (in place in ws)
    wta_kernel<256, 1><<<B * H, 256, 0, stream>>>(rates, T);
    // Stage 3: gain * V -> LIF rates (B,H,T,D), written straight into d_out
    v_rates_kernel<<<TOTAL / 256, 256, 0, stream>>>(rates, V, out, D);
    // Stage 4: WTA over the flattened T*D=16384 units of each head (in place in d_out)
    wta_kernel<1024, 16><<<B * H, 1024, 0, stream>>>(out, T * D);
}

// Round 2
// 25.530 us; speedup vs baseline: 5.1124x; 5.1124x over previous
//
#include <hip/hip_runtime.h>
#include <math.h>

// ---- reference hyperparameters ----
#define LIF_STEPS 100
#define ALPHA 0.05f        // dt / tau_rc = 0.001 / 0.02
#define V_THRESH 1.0f
#define RATE_SCALE 10.0f   // 1 / (n_steps * dt)
#define WTA_ITERS 20
#define W_INH (-0.9f)
#define W_EXC (1.1f)

// Simulate the LIF neuron exactly as the reference scan does.
__device__ __forceinline__ float lif_rate(float J) {
    float v = 0.0f;
    float cnt = 0.0f;
    #pragma unroll 4
    for (int s = 0; s < LIF_STEPS; ++s) {
        v = v + ALPHA * (J - v);          // leaky integration
        if (v >= V_THRESH) {              // spike + reset
            cnt += 1.0f;
            v = 0.0f;
        }
    }
    return cnt * RATE_SCALE;
}

// Stage 1: one wave per token; lane = dim. Coalesced loads, butterfly dot.
__global__ void qk_rates_kernel(const float* __restrict__ Q,
                                const float* __restrict__ K,
                                float* __restrict__ rates) {
    int g = blockIdx.x * blockDim.x + threadIdx.x;   // g = tok*64 + lane
    float p = Q[g] * K[g];
    #pragma unroll
    for (int off = 32; off >= 1; off >>= 1) p += __shfl_xor(p, off, 64);
    float rate = lif_rate(p);                         // all lanes redundantly (no divergence)
    if ((g & 63) == 0) rates[g >> 6] = rate;
}

// Stage 3: J = gain[token] * V, LIF rates. 1 thread / element.
__global__ void v_rates_kernel(const float* __restrict__ gains,  // (B*H*T)
                               const float* __restrict__ V,
                               float* __restrict__ out) {
    int idx = blockIdx.x * blockDim.x + threadIdx.x;
    float J = gains[idx >> 6] * V[idx];               // D == 64
    out[idx] = lif_rate(J);
}

// Iterative soft WTA over one row of N = BLOCK*ITEMS elements, in registers.
//   r <- softmax(r + 2*r + inh*sum(r)), WTA_ITERS times.
// Exact fixed-point early exit: if all elements are equal at iteration start,
// that iteration (and every later one) produces exactly 1/N per element:
// the shifted exps are all exp(0)=1, the sum of N ones is exact, and N is a
// power of two so 1/N is exact. So we write 1/N and break — bit-faithful.
// The softmax max is derived from the pre-update max: the update
// x -> x + 2x + inh*total is monotone in fl-arithmetic (rounding/fma are
// monotone per argument), so transform(max) == max(transform) bit-exactly.
template<int BLOCK, int ITEMS>
__global__ __launch_bounds__(BLOCK)
void wta_kernel(float* __restrict__ data) {
    constexpr int NW = BLOCK / 64;
    constexpr int N  = BLOCK * ITEMS;
    __shared__ float sh[3][NW];
    const int tid  = threadIdx.x;
    const int lane = tid & 63;
    const int wid  = tid >> 6;
    float* row = data + (size_t)blockIdx.x * N;

    float r[ITEMS];
    #pragma unroll
    for (int i = 0; i < ITEMS; ++i) r[i] = row[tid + i * BLOCK];

    for (int it = 0; it < WTA_ITERS; ++it) {
        // ---- pass A: (sum, min, max) in one butterfly ----
        float ls = 0.0f, lmn = r[0], lmx = r[0];
        #pragma unroll
        for (int i = 0; i < ITEMS; ++i) {
            ls += r[i]; lmn = fminf(lmn, r[i]); lmx = fmaxf(lmx, r[i]);
        }
        #pragma unroll
        for (int off = 32; off >= 1; off >>= 1) {
            ls  += __shfl_xor(ls, off, 64);
            lmn  = fminf(lmn, __shfl_xor(lmn, off, 64));
            lmx  = fmaxf(lmx, __shfl_xor(lmx, off, 64));
        }
        float total, gmn, gmx;
        if constexpr (NW > 1) {
            __syncthreads();
            if (lane == 0) { sh[0][wid] = ls; sh[1][wid] = lmn; sh[2][wid] = lmx; }
            __syncthreads();
            total = 0.0f; gmn = sh[1][0]; gmx = sh[2][0];
            #pragma unroll
            for (int w = 0; w < NW; ++w) {
                total += sh[0][w];
                gmn = fminf(gmn, sh[1][w]);
                gmx = fmaxf(gmx, sh[2][w]);
            }
        } else { total = ls; gmn = lmn; gmx = lmx; }

        if (gmn == gmx) {                 // exact fixed point reached
            #pragma unroll
            for (int i = 0; i < ITEMS; ++i) r[i] = 1.0f / (float)N;
            break;
        }

        // ---- update + softmax (max derived, one reduction saved) ----
        const float tmax = gmx + 2.0f * gmx + W_INH * total;
        float s = 0.0f;
        #pragma unroll
        for (int i = 0; i < ITEMS; ++i) {
            float e = r[i] + 2.0f * r[i] + W_INH * total;
            float p = expf(e - tmax);
            r[i] = p;
            s += p;
        }
        #pragma unroll
        for (int off = 32; off >= 1; off >>= 1) s += __shfl_xor(s, off, 64);
        float gsum;
        if constexpr (NW > 1) {
            __syncthreads();
            if (lane == 0) sh[0][wid] = s;
            __syncthreads();
            gsum = 0.0f;
            #pragma unroll
            for (int w = 0; w < NW; ++w) gsum += sh[0][w];
        } else gsum = s;

        #pragma unroll
        for (int i = 0; i < ITEMS; ++i) r[i] = r[i] / gsum;
    }

    #pragma unroll
    for (int i = 0; i < ITEMS; ++i) row[tid + i * BLOCK] = r[i];
}

extern "C" void kernel_launch(void* const* d_in, const int* in_sizes, int n_in,
                              void* d_out, int out_size, void* d_ws, size_t ws_size,
                              hipStream_t stream) {
    const float* Q = (const float*)d_in[0];
    const float* K = (const float*)d_in[1];
    const float* V = (const float*)d_in[2];
    float* out   = (float*)d_out;
    float* rates = (float*)d_ws;          // B*H*T = 4096 floats of scratch

    const int B = 2, H = 8, T = 256, D = 64;
    const int BHT   = B * H * T;          // 4096
    const int TOTAL = BHT * D;            // 262144

    // Stage 1: QK dot (wave per token, coalesced) -> LIF rates (B,H,T)
    qk_rates_kernel<<<TOTAL / 256, 256, 0, stream>>>(Q, K, rates);
    // Stage 2: WTA over T=256 tokens per head — single wave, shuffle-only
    wta_kernel<64, 4><<<B * H, 64, 0, stream>>>(rates);
    // Stage 3: gain * V -> LIF rates (B,H,T,D), straight into d_out
    v_rates_kernel<<<TOTAL / 256, 256, 0, stream>>>(rates, V, out);
    // Stage 4: WTA over T*D=16384 units per head (early-exits on uniform ctx)
    wta_kernel<1024, 16><<<B * H, 1024, 0, stream>>>(out);
}

// Round 3
// 19.742 us; speedup vs baseline: 6.6114x; 1.2932x over previous
//
#include <hip/hip_runtime.h>
#include <math.h>

// ---- reference hyperparameters ----
#define LIF_STEPS 100
#define ALPHA 0.05f        // dt / tau_rc
#define WTA_ITERS 20
#define W_INH (-0.9f)

// LIF firing rate, faithful to the reference scan.
// Exact fast path: starting at v=0, v approaches J monotonically and float
// rounding cannot push v past J (alpha*(J-v) < (J-v), rounding monotone), so
// v <= J at every step. Hence J < 1.0 (strict)  =>  no spike ever  =>  rate
// is bit-exactly 0 without simulating. J >= 1 runs the true loop.
__device__ __forceinline__ float lif_rate(float J) {
    if (J < 1.0f) return 0.0f;
    float v = 0.0f, cnt = 0.0f;
    #pragma unroll 4
    for (int s = 0; s < LIF_STEPS; ++s) {
        v = v + ALPHA * (J - v);          // leaky integration
        if (v >= 1.0f) { cnt += 1.0f; v = 0.0f; }
    }
    return cnt * 10.0f;                   // spikes / (n_steps * dt)
}

// Whole pipeline for one (b,h) head per block: 1024 threads, T=256, D=64.
__global__ __launch_bounds__(1024)
void bio_attn_kernel(const float* __restrict__ Q,
                     const float* __restrict__ K,
                     const float* __restrict__ V,
                     float* __restrict__ out) {
    constexpr int T = 256, D = 64, N = T * D;     // 16384 per head
    constexpr int NW = 16;                        // waves per block
    const int tid  = threadIdx.x;
    const int lane = tid & 63;
    const int wid  = tid >> 6;
    const size_t base = (size_t)blockIdx.x * N;

    __shared__ float sh_r[T];                     // token rates -> gains
    __shared__ float sh_red[3][NW];

    // ---- Stage 1: J = <q_t, k_t>, LIF -> rate per token (4 threads/token) ----
    {
        const int tok = tid >> 2, sub = tid & 3;
        const float4* q = (const float4*)(Q + base + tok * D + sub * 16);
        const float4* k = (const float4*)(K + base + tok * D + sub * 16);
        float p = 0.0f;
        #pragma unroll
        for (int i = 0; i < 4; ++i) {
            float4 a = q[i], b = k[i];
            p += a.x * b.x + a.y * b.y + a.z * b.z + a.w * b.w;
        }
        p += __shfl_xor(p, 1);                    // reduce across the 4 subs
        p += __shfl_xor(p, 2);
        float rate = lif_rate(p);                 // redundant on 4 lanes (no divergence)
        if (sub == 0) sh_r[tok] = rate;
    }
    __syncthreads();

    // ---- Stage 2: WTA over the T=256 rates — wave 0 only, shuffle-only ----
    // r <- softmax(r + 2r + inh*sum(r)). Exact fixed point: once all equal,
    // result is exactly 1/T forever (exp(0)=1 each, sum exact, T pow2).
    // Softmax max is derived from pre-update max (update is fl-monotone).
    if (wid == 0) {
        float r[4];
        #pragma unroll
        for (int i = 0; i < 4; ++i) r[i] = sh_r[lane + i * 64];
        for (int it = 0; it < WTA_ITERS; ++it) {
            float ls = 0.0f, mn = r[0], mx = r[0];
            #pragma unroll
            for (int i = 0; i < 4; ++i) {
                ls += r[i]; mn = fminf(mn, r[i]); mx = fmaxf(mx, r[i]);
            }
            #pragma unroll
            for (int off = 32; off >= 1; off >>= 1) {
                ls += __shfl_xor(ls, off);
                mn  = fminf(mn, __shfl_xor(mn, off));
                mx  = fmaxf(mx, __shfl_xor(mx, off));
            }
            if (mn == mx) {                        // exact fixed point
                #pragma unroll
                for (int i = 0; i < 4; ++i) r[i] = 1.0f / (float)T;
                break;
            }
            const float tmax = mx + 2.0f * mx + W_INH * ls;
            float s = 0.0f;
            #pragma unroll
            for (int i = 0; i < 4; ++i) {
                float e = r[i] + 2.0f * r[i] + W_INH * ls;
                float p = expf(e - tmax);
                r[i] = p; s += p;
            }
            #pragma unroll
            for (int off = 32; off >= 1; off >>= 1) s += __shfl_xor(s, off);
            #pragma unroll
            for (int i = 0; i < 4; ++i) r[i] = r[i] / s;
        }
        #pragma unroll
        for (int i = 0; i < 4; ++i) sh_r[lane + i * 64] = r[i];
    }
    __syncthreads();

    // ---- Stage 3: J = gain[token] * V, LIF -> context (16 elems/thread) ----
    float r[16];
    #pragma unroll
    for (int i = 0; i < 16; ++i) {
        int gi = i * 1024 + tid;                  // element within head
        float J = sh_r[gi >> 6] * V[base + gi];   // D == 64
        r[i] = lif_rate(J);                       // fast path when |J| < 1
    }

    // ---- Stage 4: WTA over the N=16384 context units, block-wide ----
    for (int it = 0; it < WTA_ITERS; ++it) {
        float ls = 0.0f, mn = r[0], mx = r[0];
        #pragma unroll
        for (int i = 0; i < 16; ++i) {
            ls += r[i]; mn = fminf(mn, r[i]); mx = fmaxf(mx, r[i]);
        }
        #pragma unroll
        for (int off = 32; off >= 1; off >>= 1) {
            ls += __shfl_xor(ls, off);
            mn  = fminf(mn, __shfl_xor(mn, off));
            mx  = fmaxf(mx, __shfl_xor(mx, off));
        }
        __syncthreads();
        if (lane == 0) { sh_red[0][wid] = ls; sh_red[1][wid] = mn; sh_red[2][wid] = mx; }
        __syncthreads();
        float total = 0.0f, gmn = sh_red[1][0], gmx = sh_red[2][0];
        #pragma unroll
        for (int w = 0; w < NW; ++w) {
            total += sh_red[0][w];
            gmn = fminf(gmn, sh_red[1][w]);
            gmx = fmaxf(gmx, sh_red[2][w]);
        }
        if (gmn == gmx) {                          // exact fixed point
            #pragma unroll
            for (int i = 0; i < 16; ++i) r[i] = 1.0f / (float)N;
            break;
        }
        const float tmax = gmx + 2.0f * gmx + W_INH * total;
        float s = 0.0f;
        #pragma unroll
        for (int i = 0; i < 16; ++i) {
            float e = r[i] + 2.0f * r[i] + W_INH * total;
            float p = expf(e - tmax);
            r[i] = p; s += p;
        }
        #pragma unroll
        for (int off = 32; off >= 1; off >>= 1) s += __shfl_xor(s, off);
        __syncthreads();
        if (lane == 0) sh_red[0][wid] = s;
        __syncthreads();
        float gsum = 0.0f;
        #pragma unroll
        for (int w = 0; w < NW; ++w) gsum += sh_red[0][w];
        #pragma unroll
        for (int i = 0; i < 16; ++i) r[i] = r[i] / gsum;
    }

    #pragma unroll
    for (int i = 0; i < 16; ++i) out[base + i * 1024 + tid] = r[i];
}

extern "C" void kernel_launch(void* const* d_in, const int* in_sizes, int n_in,
                              void* d_out, int out_size, void* d_ws, size_t ws_size,
                              hipStream_t stream) {
    const float* Q = (const float*)d_in[0];
    const float* K = (const float*)d_in[1];
    const float* V = (const float*)d_in[2];
    float* out = (float*)d_out;
    const int B = 2, H = 8;
    bio_attn_kernel<<<B * H, 1024, 0, stream>>>(Q, K, V, out);
}